// Round 3
// baseline (250.876 us; speedup 1.0000x reference)
//
#include <hip/hip_runtime.h>
#include <hip/hip_bf16.h>

#define HH 256   // hidden dim
#define HJ 128   // H/2
#define GG 512   // number of graphs

typedef __attribute__((ext_vector_type(8))) short short8;
typedef __attribute__((ext_vector_type(4))) float f32x4;

static __device__ __forceinline__ short f2bf(float f) {
  // round-to-nearest-even fp32 -> bf16 (inputs are finite)
  unsigned u = __builtin_bit_cast(unsigned, f);
  unsigned r = (u + 0x7FFFu + ((u >> 16) & 1u)) >> 16;
  return (short)r;
}

static __device__ __forceinline__ float bf2f(short b) {
  unsigned u = ((unsigned)(unsigned short)b) << 16;
  return __builtin_bit_cast(float, u);
}

// ---------------- zero-init accumulators (embraw + esum contiguous) -------
__global__ __launch_bounds__(256) void zero_kernel(float* __restrict__ p, int n) {
  const int i = blockIdx.x * 256 + threadIdx.x;
  if (i < n) p[i] = 0.f;
}

// ---------------- Kernel 0: pre-fragment W1^T into MFMA A-operand order ----
// w1a[kt*8+jt][lane] = 8 bf16: A[m=j][k] with j = jt*16+(l&15), k = kt*32+(l>>4)*8+i
__global__ __launch_bounds__(64) void w1frag_kernel(
    const float* __restrict__ W1, short8* __restrict__ w1a) {
  const int l = threadIdx.x;
  const int kt = blockIdx.x >> 3;
  const int jt = blockIdx.x & 7;
  const int j = jt * 16 + (l & 15);
  const int kb = kt * 32 + (l >> 4) * 8;
  short8 v;
#pragma unroll
  for (int i = 0; i < 8; ++i) v[i] = f2bf(W1[(size_t)(kb + i) * HJ + j]);
  w1a[blockIdx.x * 64 + l] = v;
}

// ---------------- Kernel A: fused gate MLP + softmax-weighted pooling -----
// s[n] = tanh(x[n,:]@W1 + b1)@W2  (b2 dropped: softmax shift-invariant)
// e_n = exp(s_n)  (no max-shift needed: |s| <= ~9, fp32-safe)
// atomically accumulate embraw[g,:] += e_n * x[n,:],  esum[g] += e_n
__global__ __launch_bounds__(512) void gate_pool_kernel(
    const float* __restrict__ x, const short8* __restrict__ w1a,
    const float* __restrict__ b1, const float* __restrict__ W2,
    const int* __restrict__ batch, float* __restrict__ embraw,
    float* __restrict__ esum, int N) {
  __shared__ short8 alds[4096];  // 64 KB: [kt(8)][jt(8)][lane(64)]
  const int tid = threadIdx.x;
  const int l = tid & 63;
  const int w = tid >> 6;  // wave 0..7

  // stage all A fragments (linear, coalesced, conflict-free)
#pragma unroll
  for (int i = 0; i < 8; ++i) alds[tid + i * 512] = w1a[tid + i * 512];

  const int node = blockIdx.x * 128 + w * 16 + (l & 15);
  const bool valid = node < N;
  const float* xp = x + (size_t)node * HH + (l >> 4) * 8;

  // B fragments: lane holds x[node][kt*32 + (l>>4)*8 + 0..7] as bf16
  short8 bfrag[8];
#pragma unroll
  for (int kt = 0; kt < 8; ++kt) {
    float4 f0 = make_float4(0.f, 0.f, 0.f, 0.f), f1 = f0;
    if (valid) {
      f0 = *reinterpret_cast<const float4*>(xp + kt * 32);
      f1 = *reinterpret_cast<const float4*>(xp + kt * 32 + 4);
    }
    short8 v;
    v[0] = f2bf(f0.x); v[1] = f2bf(f0.y); v[2] = f2bf(f0.z); v[3] = f2bf(f0.w);
    v[4] = f2bf(f1.x); v[5] = f2bf(f1.y); v[6] = f2bf(f1.z); v[7] = f2bf(f1.w);
    bfrag[kt] = v;
  }
  __syncthreads();

  f32x4 acc[8];
#pragma unroll
  for (int jt = 0; jt < 8; ++jt) acc[jt] = (f32x4)(0.f);

#pragma unroll
  for (int kt = 0; kt < 8; ++kt) {
#pragma unroll
    for (int jt = 0; jt < 8; ++jt) {
      acc[jt] = __builtin_amdgcn_mfma_f32_16x16x32_bf16(
          alds[(kt * 8 + jt) * 64 + l], bfrag[kt], acc[jt], 0, 0, 0);
    }
  }

  // epilogue: lane holds h[j][node] for j = jt*16 + (l>>4)*4 + r
  float sacc = 0.f;
  const int jb = (l >> 4) * 4;
#pragma unroll
  for (int jt = 0; jt < 8; ++jt) {
    const int j0 = jt * 16 + jb;
    const float4 bb = *reinterpret_cast<const float4*>(b1 + j0);
    const float4 ww = *reinterpret_cast<const float4*>(W2 + j0);
    sacc += tanhf(acc[jt][0] + bb.x) * ww.x;
    sacc += tanhf(acc[jt][1] + bb.y) * ww.y;
    sacc += tanhf(acc[jt][2] + bb.z) * ww.z;
    sacc += tanhf(acc[jt][3] + bb.w) * ww.w;
  }
  sacc += __shfl_xor(sacc, 16, 64);
  sacc += __shfl_xor(sacc, 32, 64);
  // every lane now holds s for node (l&15)

  const float e = valid ? expf(sacc) : 0.f;
  const int myg = batch[valid ? node : (N - 1)];
  const int g0 = __shfl(myg, 0, 64);
  const int g1 = __shfl(myg, 15, 64);

  for (int g = g0; g <= g1; ++g) {
    const float ew = (myg == g) ? e : 0.f;
    // scalar esum reduce over the 16 node-lanes
    float es = ew;
    es += __shfl_xor(es, 1, 64);
    es += __shfl_xor(es, 2, 64);
    es += __shfl_xor(es, 4, 64);
    es += __shfl_xor(es, 8, 64);
    // weighted x reduce (bf16 x: pooling is linear, error ~6e-5)
#pragma unroll
    for (int kt = 0; kt < 8; ++kt) {
      float v[8];
#pragma unroll
      for (int i = 0; i < 8; ++i) v[i] = bf2f(bfrag[kt][i]) * ew;
#pragma unroll
      for (int i = 0; i < 8; ++i) {
        v[i] += __shfl_xor(v[i], 1, 64);
        v[i] += __shfl_xor(v[i], 2, 64);
        v[i] += __shfl_xor(v[i], 4, 64);
        v[i] += __shfl_xor(v[i], 8, 64);
      }
      if ((l & 15) == 0) {
        float* dst = embraw + (size_t)g * HH + kt * 32 + (l >> 4) * 8;
#pragma unroll
        for (int i = 0; i < 8; ++i) atomicAdd(dst + i, v[i]);
      }
    }
    if (l == 0) atomicAdd(esum + g, es);
  }
}

// ---------------- Kernel D: context = (embraw/esum) @ Wp + bp --------------
__global__ __launch_bounds__(256) void proj_kernel(
    const float* __restrict__ embraw, const float* __restrict__ esum,
    const float* __restrict__ Wp, const float* __restrict__ bp,
    float* __restrict__ ctx) {
  __shared__ float er[HH];
  const int g = blockIdx.x;
  const int tid = threadIdx.x;
  const float es = esum[g];
  const float inv = (es > 0.f) ? 1.f / es : 0.f;
  er[tid] = embraw[(size_t)g * HH + tid] * inv;
  __syncthreads();
  float acc = bp[tid];
#pragma unroll 4
  for (int k = 0; k < HH; ++k) {
    acc = fmaf(er[k], Wp[(size_t)k * HH + tid], acc);
  }
  ctx[(size_t)g * HH + tid] = acc;
}

// ---------------- Kernel E: out[n,:] = ctx[batch[n],:] ----------------
__global__ __launch_bounds__(256) void gather_kernel(
    const float4* __restrict__ ctx4, const int* __restrict__ batch,
    float4* __restrict__ out4, long long total4) {
  const long long gid = (long long)blockIdx.x * 256 + threadIdx.x;
  if (gid >= total4) return;
  const int n = (int)(gid >> 6);  // 64 float4 per row
  const int q = (int)(gid & 63);
  out4[gid] = ctx4[(size_t)batch[n] * 64 + q];
}

extern "C" void kernel_launch(void* const* d_in, const int* in_sizes, int n_in,
                              void* d_out, int out_size, void* d_ws, size_t ws_size,
                              hipStream_t stream) {
  const float* x = (const float*)d_in[0];
  const int* batch = (const int*)d_in[1];
  const float* W1 = (const float*)d_in[2];
  const float* b1 = (const float*)d_in[3];
  const float* W2 = (const float*)d_in[4];
  // d_in[5] = b2 (unused: softmax shift-invariant)
  const float* Wp = (const float*)d_in[6];
  const float* bp = (const float*)d_in[7];
  float* out = (float*)d_out;

  const int N = in_sizes[1];
  const int G = GG;

  // workspace layout (16B aligned)
  char* wsp = (char*)d_ws;
  short8* w1a = (short8*)wsp;              // 4096 short8 = 64 KB
  size_t off = 4096 * sizeof(short8);
  float* embraw = (float*)(wsp + off);     // G*H floats   (zeroed)
  off += (size_t)G * HH * 4;
  float* esum = (float*)(wsp + off);       // G floats     (zeroed)
  off += (size_t)G * 4;
  float* ctx = (float*)(wsp + off);        // G*H floats

  // zero accumulators (embraw + esum are contiguous)
  {
    const int nz = G * HH + G;
    zero_kernel<<<dim3((nz + 255) / 256), 256, 0, stream>>>(embraw, nz);
  }
  // fragment W1
  w1frag_kernel<<<dim3(64), 64, 0, stream>>>(W1, w1a);
  // fused gate + pool
  {
    dim3 grid((N + 127) / 128);
    gate_pool_kernel<<<grid, 512, 0, stream>>>(x, w1a, b1, W2, batch, embraw,
                                               esum, N);
  }
  // projection (with esum division fused)
  proj_kernel<<<dim3(G), 256, 0, stream>>>(embraw, esum, Wp, bp, ctx);
  // gather/broadcast to nodes
  {
    const long long total4 = (long long)N * (HH / 4);
    dim3 grid((unsigned)((total4 + 255) / 256));
    gather_kernel<<<grid, 256, 0, stream>>>((const float4*)ctx, batch,
                                            (float4*)out, total4);
  }
}

// Round 4
// 178.303 us; speedup vs baseline: 1.4070x; 1.4070x over previous
//
#include <hip/hip_runtime.h>
#include <hip/hip_bf16.h>

#define HH 256   // hidden dim
#define HJ 128   // H/2
#define GG 512   // number of graphs

typedef __attribute__((ext_vector_type(8))) short short8;
typedef __attribute__((ext_vector_type(4))) float f32x4;

static __device__ __forceinline__ short f2bf(float f) {
  // round-to-nearest-even fp32 -> bf16 (inputs are finite)
  unsigned u = __builtin_bit_cast(unsigned, f);
  unsigned r = (u + 0x7FFFu + ((u >> 16) & 1u)) >> 16;
  return (short)r;
}

// ---------------- Kernel 0: pre-fragment W1^T into MFMA A-operand order ----
// w1a[kt*8+jt][lane] = 8 bf16: A[m=j][k] with j = jt*16+(l&15), k = kt*32+(l>>4)*8+i
__global__ __launch_bounds__(64) void w1frag_kernel(
    const float* __restrict__ W1, short8* __restrict__ w1a) {
  const int l = threadIdx.x;
  const int kt = blockIdx.x >> 3;
  const int jt = blockIdx.x & 7;
  const int j = jt * 16 + (l & 15);
  const int kb = kt * 32 + (l >> 4) * 8;
  short8 v;
#pragma unroll
  for (int i = 0; i < 8; ++i) v[i] = f2bf(W1[(size_t)(kb + i) * HJ + j]);
  w1a[blockIdx.x * 64 + l] = v;
}

// ---------------- Kernel A: gating MLP via bf16 MFMA -> e = exp(s) --------
// s[n] = tanh(x[n,:] @ W1 + b1) @ W2   (b2 dropped: softmax shift-invariant)
// e[n] = exp(s[n])  — max-free softmax is fp32-safe since |s| <= ~10.
__global__ __launch_bounds__(512) void gate_mfma_kernel(
    const float* __restrict__ x, const short8* __restrict__ w1a,
    const float* __restrict__ b1, const float* __restrict__ W2,
    float* __restrict__ e, int N) {
  __shared__ short8 alds[4096];  // 64 KB: [kt(8)][jt(8)][lane(64)]
  const int tid = threadIdx.x;
  const int l = tid & 63;
  const int w = tid >> 6;  // wave 0..7

  // stage all A fragments (linear, coalesced, conflict-free)
#pragma unroll
  for (int i = 0; i < 8; ++i) alds[tid + i * 512] = w1a[tid + i * 512];

  const int node = blockIdx.x * 128 + w * 16 + (l & 15);
  const bool valid = node < N;
  const float* xp = x + (size_t)node * HH + (l >> 4) * 8;

  // B fragments: lane holds x[node][kt*32 + (l>>4)*8 + 0..7] as bf16
  short8 bfrag[8];
#pragma unroll
  for (int kt = 0; kt < 8; ++kt) {
    float4 f0 = make_float4(0.f, 0.f, 0.f, 0.f), f1 = f0;
    if (valid) {
      f0 = *reinterpret_cast<const float4*>(xp + kt * 32);
      f1 = *reinterpret_cast<const float4*>(xp + kt * 32 + 4);
    }
    short8 v;
    v[0] = f2bf(f0.x); v[1] = f2bf(f0.y); v[2] = f2bf(f0.z); v[3] = f2bf(f0.w);
    v[4] = f2bf(f1.x); v[5] = f2bf(f1.y); v[6] = f2bf(f1.z); v[7] = f2bf(f1.w);
    bfrag[kt] = v;
  }
  __syncthreads();

  f32x4 acc[8];
#pragma unroll
  for (int jt = 0; jt < 8; ++jt) acc[jt] = (f32x4)(0.f);

#pragma unroll
  for (int kt = 0; kt < 8; ++kt) {
#pragma unroll
    for (int jt = 0; jt < 8; ++jt) {
      acc[jt] = __builtin_amdgcn_mfma_f32_16x16x32_bf16(
          alds[(kt * 8 + jt) * 64 + l], bfrag[kt], acc[jt], 0, 0, 0);
    }
  }

  // epilogue: lane holds h[j][node] for j = jt*16 + (l>>4)*4 + r
  float sacc = 0.f;
  const int jb = (l >> 4) * 4;
#pragma unroll
  for (int jt = 0; jt < 8; ++jt) {
    const int j0 = jt * 16 + jb;
    const float4 bb = *reinterpret_cast<const float4*>(b1 + j0);
    const float4 ww = *reinterpret_cast<const float4*>(W2 + j0);
    sacc += tanhf(acc[jt][0] + bb.x) * ww.x;
    sacc += tanhf(acc[jt][1] + bb.y) * ww.y;
    sacc += tanhf(acc[jt][2] + bb.z) * ww.z;
    sacc += tanhf(acc[jt][3] + bb.w) * ww.w;
  }
  sacc += __shfl_xor(sacc, 16, 64);
  sacc += __shfl_xor(sacc, 32, 64);
  if ((l < 16) && valid) e[node] = expf(sacc);
}

// ---------------- segment offsets from sorted batch ----------------
__global__ __launch_bounds__(256) void segstart_kernel(
    const int* __restrict__ batch, int* __restrict__ segstart, int N, int G) {
  const int n = blockIdx.x * 256 + threadIdx.x;
  if (n >= N) return;
  const int b = batch[n];
  const int p = (n == 0) ? -1 : batch[n - 1];
  for (int g = p + 1; g <= b; ++g) segstart[g] = n;
  if (n == N - 1) {
    for (int g = b + 1; g <= G; ++g) segstart[g] = N;
  }
}

// ---------------- Kernel C: weighted pool, h-sliced ----------------
// grid (G, 4): block (g, hq) owns emb[g, hq*64 .. hq*64+63] exclusively.
// 256 threads = 4 waves; wave ng handles nodes n0+ng, n0+ng+4, ...
__global__ __launch_bounds__(256) void pool2_kernel(
    const float* __restrict__ x, const float* __restrict__ e,
    const int* __restrict__ segstart, float* __restrict__ embraw,
    float* __restrict__ esum) {
  __shared__ float red[4][64];
  __shared__ float sred[4];
  const int g = blockIdx.x;
  const int hq = blockIdx.y;
  const int lane = threadIdx.x & 63;
  const int ng = threadIdx.x >> 6;
  const int h = hq * 64 + lane;
  const int n0 = segstart[g];
  const int n1 = segstart[g + 1];

  float acc = 0.f;
  for (int n = n0 + ng; n < n1; n += 4) {
    acc = fmaf(e[n], x[(size_t)n * HH + h], acc);
  }
  red[ng][lane] = acc;

  // esum only in hq==0 blocks
  float es = 0.f;
  if (hq == 0) {
    for (int n = n0 + (int)threadIdx.x; n < n1; n += 256) es += e[n];
    for (int off = 32; off > 0; off >>= 1) es += __shfl_xor(es, off, 64);
    if (lane == 0) sred[ng] = es;
  }
  __syncthreads();

  if (ng == 0) {
    embraw[(size_t)g * HH + h] =
        red[0][lane] + red[1][lane] + red[2][lane] + red[3][lane];
    if (hq == 0 && lane == 0) {
      esum[g] = sred[0] + sred[1] + sred[2] + sred[3];
    }
  }
}

// ---------------- Kernel D: context = (embraw/esum) @ Wp + bp --------------
__global__ __launch_bounds__(256) void proj_kernel(
    const float* __restrict__ embraw, const float* __restrict__ esum,
    const float* __restrict__ Wp, const float* __restrict__ bp,
    float* __restrict__ ctx) {
  __shared__ float er[HH];
  const int g = blockIdx.x;
  const int tid = threadIdx.x;
  const float es = esum[g];
  const float inv = (es > 0.f) ? 1.f / es : 0.f;
  er[tid] = embraw[(size_t)g * HH + tid] * inv;
  __syncthreads();
  float acc = bp[tid];
#pragma unroll 4
  for (int k = 0; k < HH; ++k) {
    acc = fmaf(er[k], Wp[(size_t)k * HH + tid], acc);
  }
  ctx[(size_t)g * HH + tid] = acc;
}

// ---------------- Kernel E: out[n,:] = ctx[batch[n],:] ----------------
__global__ __launch_bounds__(256) void gather_kernel(
    const float4* __restrict__ ctx4, const int* __restrict__ batch,
    float4* __restrict__ out4, long long total4) {
  const long long gid = (long long)blockIdx.x * 256 + threadIdx.x;
  if (gid >= total4) return;
  const int n = (int)(gid >> 6);  // 64 float4 per row
  const int q = (int)(gid & 63);
  out4[gid] = ctx4[(size_t)batch[n] * 64 + q];
}

extern "C" void kernel_launch(void* const* d_in, const int* in_sizes, int n_in,
                              void* d_out, int out_size, void* d_ws, size_t ws_size,
                              hipStream_t stream) {
  const float* x = (const float*)d_in[0];
  const int* batch = (const int*)d_in[1];
  const float* W1 = (const float*)d_in[2];
  const float* b1 = (const float*)d_in[3];
  const float* W2 = (const float*)d_in[4];
  // d_in[5] = b2 (unused: softmax shift-invariant)
  const float* Wp = (const float*)d_in[6];
  const float* bp = (const float*)d_in[7];
  float* out = (float*)d_out;

  const int N = in_sizes[1];
  const int G = GG;

  // workspace layout (16B aligned)
  char* wsp = (char*)d_ws;
  short8* w1a = (short8*)wsp;              // 4096 short8 = 64 KB
  size_t off = 4096 * sizeof(short8);
  float* e = (float*)(wsp + off);          // N floats
  off += ((size_t)N * 4 + 15) & ~15ull;
  int* segstart = (int*)(wsp + off);       // G+1 ints
  off += (((size_t)(G + 1) * 4 + 15) & ~15ull);
  float* embraw = (float*)(wsp + off);     // G*H floats
  off += (size_t)G * HH * 4;
  float* esum = (float*)(wsp + off);       // G floats
  off += (((size_t)G * 4 + 15) & ~15ull);
  float* ctx = (float*)(wsp + off);        // G*H floats

  // fragment W1
  w1frag_kernel<<<dim3(64), 64, 0, stream>>>(W1, w1a);
  // gate scores -> e = exp(s)
  {
    dim3 grid((N + 127) / 128);
    gate_mfma_kernel<<<grid, 512, 0, stream>>>(x, w1a, b1, W2, e, N);
  }
  // segment offsets
  {
    dim3 grid((N + 255) / 256);
    segstart_kernel<<<grid, 256, 0, stream>>>(batch, segstart, N, G);
  }
  // weighted pool (h-sliced, no atomics)
  pool2_kernel<<<dim3(G, 4), 256, 0, stream>>>(x, e, segstart, embraw, esum);
  // projection (esum division fused)
  proj_kernel<<<dim3(G), 256, 0, stream>>>(embraw, esum, Wp, bp, ctx);
  // gather/broadcast to nodes
  {
    const long long total4 = (long long)N * (HH / 4);
    dim3 grid((unsigned)((total4 + 255) / 256));
    gather_kernel<<<grid, 256, 0, stream>>>((const float4*)ctx, batch,
                                            (float4*)out, total4);
  }
}